// Round 20
// baseline (159.734 us; speedup 1.0000x reference)
//
#include <hip/hip_runtime.h>
#include <math.h>

#define N_NODES 100000
#define N_EDGES 1600000

static inline size_t align256(size_t x) { return (x + 255) & ~((size_t)255); }

constexpr int NB = (N_NODES + 255) / 256;  // 391 buckets (node>>8)
constexpr int CAP = 5120;                  // bucket capacity
constexpr int PHB = 128;                   // partition blocks per pass (x2 passes)
constexpr int PT = 512;                    // partition threads
constexpr int PCHUNK = N_EDGES / PHB;      // 12500
constexpr int NOCT = N_NODES / 8;          // 12500
constexpr int NTILE = N_NODES / 16;        // 6250 16-node tiles

typedef _Float16 h2 __attribute__((ext_vector_type(2)));
typedef _Float16 half8 __attribute__((ext_vector_type(8)));
typedef float f32x2 __attribute__((ext_vector_type(2)));
typedef float f32x4 __attribute__((ext_vector_type(4)));
typedef unsigned u32x2 __attribute__((ext_vector_type(2)));
union HU { float f; unsigned u; h2 h; };

#if __has_builtin(__builtin_amdgcn_fdot2)
#endif

#if __has_builtin(__builtin_amdgcn_cvt_pk_f32_fp8) && __has_builtin(__builtin_amdgcn_cvt_pk_fp8_f32)
#define FP8_HW 1
#else
#include <hip/hip_fp8.h>
#endif

// decode 4 fp8 (one u32) -> two f32x2   (u == 0 decodes to zeros)
__device__ inline void dec4(unsigned u, f32x2& lo, f32x2& hi) {
#ifdef FP8_HW
  lo = __builtin_amdgcn_cvt_pk_f32_fp8((int)u, false);
  hi = __builtin_amdgcn_cvt_pk_f32_fp8((int)u, true);
#else
  __hip_fp8_e4m3 v0, v1, v2, v3;
  v0.__x = u & 0xFF; v1.__x = (u >> 8) & 0xFF;
  v2.__x = (u >> 16) & 0xFF; v3.__x = (u >> 24) & 0xFF;
  lo.x = (float)v0; lo.y = (float)v1; hi.x = (float)v2; hi.y = (float)v3;
#endif
}

__device__ inline unsigned enc4(float a, float b, float c, float d) {
#ifdef FP8_HW
  int w = __builtin_amdgcn_cvt_pk_fp8_f32(a, b, 0, false);
  w = __builtin_amdgcn_cvt_pk_fp8_f32(c, d, w, true);
  return (unsigned)w;
#else
  return (unsigned)__hip_fp8_e4m3(a).__x | ((unsigned)__hip_fp8_e4m3(b).__x << 8) |
         ((unsigned)__hip_fp8_e4m3(c).__x << 16) | ((unsigned)__hip_fp8_e4m3(d).__x << 24);
#endif
}

// 8 fp8 (two u32) -> 8 fp16 packed in a uint4
__device__ inline uint4 fp8x8_to_h8(unsigned ux, unsigned uy) {
  f32x2 lo, hi;
  HU p0, p1, p2, p3;
  dec4(ux, lo, hi);
  p0.h.x = (_Float16)lo.x; p0.h.y = (_Float16)lo.y;
  p1.h.x = (_Float16)hi.x; p1.h.y = (_Float16)hi.y;
  dec4(uy, lo, hi);
  p2.h.x = (_Float16)lo.x; p2.h.y = (_Float16)lo.y;
  p3.h.x = (_Float16)hi.x; p3.h.y = (_Float16)hi.y;
  return make_uint4(p0.u, p1.u, p2.u, p3.u);
}

// ---------------- K1: dual partition, ONE pass per block ----------------

__global__ __launch_bounds__(PT) void partition_kernel(
    const float* __restrict__ x, unsigned char* __restrict__ h0,
    const int* __restrict__ src, const int* __restrict__ dst,
    int* __restrict__ gfillD, int* __restrict__ gfillS,
    unsigned* __restrict__ pairsD, unsigned* __restrict__ pairsS) {
  __shared__ unsigned ents[PCHUNK];       // 50.0 KB
  __shared__ unsigned short bkt[PCHUNK];  // 25.0 KB
  __shared__ int hist[NB], lfill[NB], delta[NB];
  __shared__ int sc[PT];

  const int blk = blockIdx.x & (PHB - 1);
  const int pass = blockIdx.x >> 7;       // 0: by-dst, 1: by-src
  const int t = threadIdx.x;
  const int e0 = blk * PCHUNK;
  const int* __restrict__ key = pass ? src : dst;
  const int* __restrict__ val = pass ? dst : src;
  int* __restrict__ gfill = pass ? gfillS : gfillD;
  unsigned* __restrict__ out = pass ? pairsS : pairsD;

  for (int i = t; i < NB; i += PT) hist[i] = 0;
  __syncthreads();
  for (int i = t; i < PCHUNK; i += PT) atomicAdd(&hist[key[e0 + i] >> 8], 1);
  __syncthreads();
  int v = (t < NB) ? hist[t] : 0;
  sc[t] = v;
  __syncthreads();
  for (int off = 1; off < PT; off <<= 1) {
    int a = (t >= off) ? sc[t - off] : 0;
    __syncthreads();
    sc[t] += a;
    __syncthreads();
  }
  if (t < NB) {
    int excl = sc[t] - v;
    lfill[t] = excl;
    int gb = atomicAdd(&gfill[t * 16], v);
    delta[t] = t * CAP + gb - excl;
  }
  __syncthreads();
  for (int i = t; i < PCHUNK; i += PT) {
    int k = key[e0 + i], w = val[e0 + i];
    int b = k >> 8;
    int p = atomicAdd(&lfill[b], 1);
    ents[p] = (unsigned)w | ((unsigned)(k & 255) << 17);
    bkt[p] = (unsigned short)b;
  }
  __syncthreads();
  for (int i = t; i < PCHUNK; i += PT) out[delta[bkt[i]] + i] = ents[i];

  // fused x -> fp8 convert (grid-stride over all 256 blocks)
  const int gtid = blockIdx.x * PT + t;
  const int nth = gridDim.x * PT;
  for (int i = gtid; i < N_NODES * 8; i += nth) {
    float4 a = ((const float4*)x)[2 * i];
    float4 b = ((const float4*)x)[2 * i + 1];
    ((uint2*)h0)[i] = make_uint2(enc4(a.x, a.y, a.z, a.w), enc4(b.x, b.y, b.z, b.w));
  }
}

// ---------------- K2: per-dst-bucket LDS counting sort ----------------

__global__ __launch_bounds__(256) void csr_kernel(const unsigned* __restrict__ pairs,
                                                  const int* __restrict__ bfill,
                                                  int* __restrict__ col,
                                                  int* __restrict__ rowptr,
                                                  int* __restrict__ cnt,
                                                  float* __restrict__ invdeg) {
  __shared__ int hist[256], sc[256], offs[256];
  const int b = blockIdx.x;
  const int t = threadIdx.x;
  hist[t] = 0;
  __syncthreads();
  const int count = bfill[b * 16];
  const int base = b * CAP;
  const unsigned* bp = pairs + (size_t)b * CAP;
  for (int i = t; i < count; i += 256) atomicAdd(&hist[(bp[i] >> 17) & 255], 1);
  __syncthreads();
  int v = hist[t];
  sc[t] = v;
  __syncthreads();
  for (int off = 1; off < 256; off <<= 1) {
    int a = (t >= off) ? sc[t - off] : 0;
    __syncthreads();
    sc[t] += a;
    __syncthreads();
  }
  const int excl = sc[t] - v;
  offs[t] = base + excl;
  const int node = b * 256 + t;
  if (node < N_NODES) {
    rowptr[node] = base + excl;
    cnt[node] = v;
    invdeg[node] = 1.0f / (float)((v > 0) ? v : 1);
  }
  __syncthreads();
  for (int i = t; i < count; i += 256) {
    unsigned e = bp[i];
    int p = atomicAdd(&offs[(e >> 17) & 255], 1);
    col[p] = (int)(e & 0x1FFFF);
  }
}

// ---------------- K3: coef via per-src-bucket LDS accumulation ----------------

__global__ __launch_bounds__(256) void coef_kernel(const unsigned* __restrict__ pairsS,
                                                   const int* __restrict__ gfillS,
                                                   const float* __restrict__ invdeg,
                                                   float* __restrict__ coef) {
  __shared__ float cl[256];
  const int b = blockIdx.x;
  const int t = threadIdx.x;
  cl[t] = 0.0f;
  __syncthreads();
  const int count = gfillS[b * 16];
  const unsigned* bp = pairsS + (size_t)b * CAP;
  for (int i = t; i < count; i += 256) {
    unsigned e = bp[i];
    atomicAdd(&cl[(e >> 17) & 255], invdeg[e & 0x1FFFF]);
  }
  __syncthreads();
  const int node = b * 256 + t;
  if (node < N_NODES) coef[node] = cl[t];
}

// ---------------- K4: gather/mean (latency path; aggr fp8) ----------------
// col reads + aggr writes are NONTEMPORAL so they don't evict h from L2;
// h reads stay temporal (the only data with reuse).

__global__ __launch_bounds__(256) void gather_kernel(
    const unsigned char* __restrict__ hin, const int* __restrict__ rowptr,
    const int* __restrict__ cnt, const int* __restrict__ col,
    uint2* __restrict__ aggr8) {
  const int tid = threadIdx.x;
  const int lane = tid & 63;
  const int wv = tid >> 6;
  const int slot = lane >> 3;   // 0..7
  const int c = lane & 7;       // channel octet
  const int wid = blockIdx.x * 4 + wv;
  const int nwaves = gridDim.x * 4;
  const uint2* __restrict__ hrows = (const uint2*)hin;

  for (int oct = wid; oct < NOCT; oct += nwaves) {
    const int node = oct * 8 + slot;
    const int deg = cnt[node];
    const int* cp = col + rowptr[node];
    f32x2 a01 = {0.f, 0.f}, a23 = {0.f, 0.f}, a45 = {0.f, 0.f}, a67 = {0.f, 0.f};
    for (int e = 0; e < deg; e += 16) {
      uint2 u[16];
#pragma unroll
      for (int i = 0; i < 16; ++i) {
        int idx = (e + i < deg) ? (e + i) : (deg - 1);
        int s = __builtin_nontemporal_load(cp + idx);
        u[i] = hrows[s * 8 + c];
      }
#pragma unroll
      for (int i = 0; i < 16; ++i) {
        const bool valid = (e + i) < deg;
        unsigned ux = valid ? u[i].x : 0u;
        unsigned uy = valid ? u[i].y : 0u;
        f32x2 lo, hi;
        dec4(ux, lo, hi); a01 += lo; a23 += hi;
        dec4(uy, lo, hi); a45 += lo; a67 += hi;
      }
    }
    const float inv = (deg > 0) ? (1.0f / (float)deg) : 0.0f;
    a01 *= inv; a23 *= inv; a45 *= inv; a67 *= inv;
    u32x2 outv = {enc4(a01.x, a01.y, a23.x, a23.y), enc4(a45.x, a45.y, a67.x, a67.y)};
    __builtin_nontemporal_store(outv, (u32x2*)&aggr8[(size_t)node * 8 + c]);
  }
}

// ---------------- K5: transform via MFMA (aggr fp8) ----------------

template <bool WRITE_OUT, bool DO_SUMS>
__global__ __launch_bounds__(256) void transform_kernel(
    const unsigned char* __restrict__ hin, const unsigned char* __restrict__ aggr8,
    const float* __restrict__ wl, const float* __restrict__ bl,
    const float* __restrict__ wr,
    const float* __restrict__ g, const float* __restrict__ be,
    const float* __restrict__ m, const float* __restrict__ v,
    unsigned char* __restrict__ hout, const float* __restrict__ coef,
    float* __restrict__ sums) {
  __shared__ _Float16 Wt[64][136];     // W~[j][k], padded stride
  __shared__ _Float16 Xs[4][16][136];  // per-wave X tile
  __shared__ float Ts[4][16][68];      // per-wave transpose buf
  __shared__ float scaleS[64], shiftS[64];
  __shared__ float redS[4][128];

  const int tid = threadIdx.x;
  {
    int j = tid >> 2, kp = (tid & 3) * 32;
    for (int kk = 0; kk < 32; ++kk) {
      int k = kp + kk;
      float val = (k < 64) ? wl[j * 64 + k] : wr[j * 64 + (k - 64)];
      Wt[j][k] = (_Float16)val;
    }
  }
  if (tid < 64) {
    float sc = rsqrtf(v[tid] + 1e-5f) * g[tid];
    scaleS[tid] = sc;
    shiftS[tid] = bl[tid] * sc + be[tid] - m[tid] * sc;
  }
  __syncthreads();

  const int lane = tid & 63;
  const int wv = tid >> 6;
  const int c = lane & 15;
  const int gq = lane >> 4;            // k-group / row-group
  const int wid = blockIdx.x * 4 + wv;
  const int nwv = gridDim.x * 4;
  float accs[4] = {0.f, 0.f, 0.f, 0.f};
  float accs2[4] = {0.f, 0.f, 0.f, 0.f};

  for (int tile = wid; tile < NTILE; tile += nwv) {
    const int nb = tile * 16;

    // ---- stage X (same-wave produce/consume, no barrier) ----
    {
      int node = lane >> 2, q4 = lane & 3;   // 16B per lane covers 16 rows x 64B
      uint4 av = ((const uint4*)(aggr8 + (size_t)nb * 64))[lane];
      *(uint4*)&Xs[wv][node][q4 * 16] = fp8x8_to_h8(av.x, av.y);
      *(uint4*)&Xs[wv][node][q4 * 16 + 8] = fp8x8_to_h8(av.z, av.w);
      uint4 ov = ((const uint4*)(hin + (size_t)nb * 64))[lane];
      *(uint4*)&Xs[wv][node][64 + q4 * 16] = fp8x8_to_h8(ov.x, ov.y);
      *(uint4*)&Xs[wv][node][64 + q4 * 16 + 8] = fp8x8_to_h8(ov.z, ov.w);
    }

    // ---- A fragments (reused across 4 col-tiles) ----
    half8 A[4];
#pragma unroll
    for (int mm = 0; mm < 4; ++mm)
      A[mm] = *(const half8*)&Xs[wv][c][mm * 32 + gq * 8];

    f32x4 acc[4];
#pragma unroll
    for (int t = 0; t < 4; ++t) {
      acc[t] = (f32x4){0.f, 0.f, 0.f, 0.f};
#pragma unroll
      for (int mm = 0; mm < 4; ++mm) {
        half8 B = *(const half8*)&Wt[t * 16 + c][mm * 32 + gq * 8];
        acc[t] = __builtin_amdgcn_mfma_f32_16x16x32_f16(A[mm], B, acc[t], 0, 0, 0);
      }
    }

    // ---- epilogue: BN + ReLU ----
    float cf[4];
    if (DO_SUMS) {
#pragma unroll
      for (int r = 0; r < 4; ++r) cf[r] = coef[nb + gq * 4 + r];
    }
#pragma unroll
    for (int t = 0; t < 4; ++t) {
      const int colj = t * 16 + c;
      const float sc = scaleS[colj], sh = shiftS[colj];
#pragma unroll
      for (int r = 0; r < 4; ++r) {
        float o = fmaxf(acc[t][r] * sc + sh, 0.0f);
        if (DO_SUMS) {
          accs[t] += o;
          accs2[t] += cf[r] * o;
        }
        if (WRITE_OUT) Ts[wv][gq * 4 + r][colj] = o;
      }
    }

    if (WRITE_OUT) {
      int node = lane >> 4, q = lane & 15;
#pragma unroll
      for (int i = 0; i < 4; ++i) {
        float4 vv = *(float4*)&Ts[wv][node + 4 * i][q * 4];
        ((unsigned*)hout)[(size_t)(nb + node + 4 * i) * 16 + q] =
            enc4(vv.x, vv.y, vv.z, vv.w);
      }
    }
  }

  if (DO_SUMS) {
#pragma unroll
    for (int t = 0; t < 4; ++t) {
      float a = accs[t], b2 = accs2[t];
      a += __shfl_xor(a, 16); a += __shfl_xor(a, 32);
      b2 += __shfl_xor(b2, 16); b2 += __shfl_xor(b2, 32);
      if (lane < 16) {
        redS[wv][t * 16 + lane] = a;
        redS[wv][64 + t * 16 + lane] = b2;
      }
    }
    __syncthreads();
    if (tid < 128) {
      float tot = redS[0][tid] + redS[1][tid] + redS[2][tid] + redS[3][tid];
      atomicAdd(&sums[tid], tot);
    }
  }
}

// ---------------- collapsed layer 2 + classifier + sigmoid ----------------

__global__ void final_kernel(const float* __restrict__ sums,
                             const float* __restrict__ wl2, const float* __restrict__ bl2,
                             const float* __restrict__ wr2,
                             const float* __restrict__ cw1, const float* __restrict__ cb1,
                             const float* __restrict__ cw2, const float* __restrict__ cb2,
                             float* __restrict__ out) {
  __shared__ float maS[64], mhS[64], m3S[64], tS[64];
  int j = threadIdx.x;  // 64 threads
  float invN = 1.0f / (float)N_NODES;
  mhS[j] = sums[j] * invN;        // mean of h2
  maS[j] = sums[64 + j] * invN;   // mean of aggr3
  __syncthreads();
  float acc = bl2[j];
#pragma unroll
  for (int k = 0; k < 64; ++k)
    acc += wl2[j * 64 + k] * maS[k] + wr2[j * 64 + k] * mhS[k];
  m3S[j] = acc;
  __syncthreads();
  float c = cb1[j];
#pragma unroll
  for (int k = 0; k < 64; ++k) c += cw1[j * 64 + k] * m3S[k];
  tS[j] = fmaxf(c, 0.f);
  __syncthreads();
  float r = tS[j] * cw2[j];
#pragma unroll
  for (int off = 32; off > 0; off >>= 1) r += __shfl_down(r, off);
  if (j == 0) out[0] = 1.0f / (1.0f + expf(-(r + cb2[0])));
}

// ---------------- host launcher ----------------

extern "C" void kernel_launch(void* const* d_in, const int* in_sizes, int n_in,
                              void* d_out, int out_size, void* d_ws, size_t ws_size,
                              hipStream_t stream) {
  const float* x   = (const float*)d_in[0];
  const int* ei    = (const int*)d_in[1];
  const float* wl0 = (const float*)d_in[2];
  const float* bl0 = (const float*)d_in[3];
  const float* wr0 = (const float*)d_in[4];
  const float* wl1 = (const float*)d_in[5];
  const float* bl1 = (const float*)d_in[6];
  const float* wr1 = (const float*)d_in[7];
  const float* wl2 = (const float*)d_in[8];
  const float* bl2 = (const float*)d_in[9];
  const float* wr2 = (const float*)d_in[10];
  const float* g0  = (const float*)d_in[11];
  const float* be0 = (const float*)d_in[12];
  const float* m0  = (const float*)d_in[13];
  const float* v0  = (const float*)d_in[14];
  const float* g1  = (const float*)d_in[15];
  const float* be1 = (const float*)d_in[16];
  const float* m1  = (const float*)d_in[17];
  const float* v1  = (const float*)d_in[18];
  const float* cw1 = (const float*)d_in[19];
  const float* cb1 = (const float*)d_in[20];
  const float* cw2 = (const float*)d_in[21];
  const float* cb2 = (const float*)d_in[22];

  const int* srcp = ei;            // edge_index[0]
  const int* dstp = ei + N_EDGES;  // edge_index[1]

  char* ws = (char*)d_ws;
  size_t off = 0;
  auto alloc = [&](size_t bytes) {
    void* p = ws + off;
    off = align256(off + bytes);
    return p;
  };
  // gfillD | gfillS | sums contiguous -> ONE memset
  int* gfillD      = (int*)alloc((size_t)512 * 16 * 4);   // 32 KB
  int* gfillS      = (int*)alloc((size_t)512 * 16 * 4);   // 32 KB
  float* sums      = (float*)alloc(128 * 4);              // 512 B
  unsigned* pairsD = (unsigned*)alloc((size_t)NB * CAP * 4);  // ~8 MB
  unsigned* pairsS = (unsigned*)alloc((size_t)NB * CAP * 4);  // ~8 MB
  int* rowptr      = (int*)alloc((size_t)N_NODES * 4);
  int* cnt         = (int*)alloc((size_t)N_NODES * 4);
  float* invdeg    = (float*)alloc((size_t)N_NODES * 4);
  float* coef      = (float*)alloc((size_t)N_NODES * 4);
  int* col         = (int*)alloc((size_t)NB * CAP * 4);       // padded per bucket
  unsigned char* h0 = (unsigned char*)alloc((size_t)N_NODES * 64);
  unsigned char* h1 = (unsigned char*)alloc((size_t)N_NODES * 64);
  uint2* aggr8     = (uint2*)alloc((size_t)N_NODES * 64);     // fp8 aggr, 6.4 MB
  (void)off; (void)ws_size; (void)in_sizes; (void)n_in; (void)out_size;

  (void)hipMemsetAsync(gfillD, 0, (size_t)512 * 16 * 4 * 2 + 512, stream);

  partition_kernel<<<256, PT, 0, stream>>>(x, h0, srcp, dstp,
                                           gfillD, gfillS, pairsD, pairsS);
  csr_kernel<<<NB, 256, 0, stream>>>(pairsD, gfillD, col, rowptr, cnt, invdeg);
  coef_kernel<<<NB, 256, 0, stream>>>(pairsS, gfillS, invdeg, coef);

  // layer 0
  gather_kernel<<<2048, 256, 0, stream>>>(h0, rowptr, cnt, col, aggr8);
  transform_kernel<true, false><<<512, 256, 0, stream>>>(
      h0, (const unsigned char*)aggr8, wl0, bl0, wr0, g0, be0, m0, v0,
      h1, nullptr, nullptr);
  // layer 1 (+ collapsed layer 2 sums)
  gather_kernel<<<2048, 256, 0, stream>>>(h1, rowptr, cnt, col, aggr8);
  transform_kernel<false, true><<<512, 256, 0, stream>>>(
      h1, (const unsigned char*)aggr8, wl1, bl1, wr1, g1, be1, m1, v1,
      nullptr, coef, sums);

  final_kernel<<<1, 64, 0, stream>>>(sums, wl2, bl2, wr2, cw1, cb1, cw2, cb2,
                                     (float*)d_out);
}

// Round 21
// 141.682 us; speedup vs baseline: 1.1274x; 1.1274x over previous
//
#include <hip/hip_runtime.h>
#include <math.h>

#define N_NODES 100000
#define N_EDGES 1600000

static inline size_t align256(size_t x) { return (x + 255) & ~((size_t)255); }

constexpr int NB = (N_NODES + 255) / 256;  // 391 buckets (node>>8)
constexpr int CAP = 5120;                  // bucket capacity
constexpr int PHB = 128;                   // partition blocks per pass (x2 passes)
constexpr int PT = 512;                    // partition threads
constexpr int PCHUNK = N_EDGES / PHB;      // 12500
constexpr int NOCT = N_NODES / 8;          // 12500
constexpr int NTILE = N_NODES / 16;        // 6250 16-node tiles

typedef _Float16 h2 __attribute__((ext_vector_type(2)));
typedef _Float16 half8 __attribute__((ext_vector_type(8)));
typedef float f32x2 __attribute__((ext_vector_type(2)));
typedef float f32x4 __attribute__((ext_vector_type(4)));
union HU { float f; unsigned u; h2 h; };

#if __has_builtin(__builtin_amdgcn_cvt_pk_f32_fp8) && __has_builtin(__builtin_amdgcn_cvt_pk_fp8_f32)
#define FP8_HW 1
#else
#include <hip/hip_fp8.h>
#endif

// decode 4 fp8 (one u32) -> two f32x2   (u == 0 decodes to zeros)
__device__ inline void dec4(unsigned u, f32x2& lo, f32x2& hi) {
#ifdef FP8_HW
  lo = __builtin_amdgcn_cvt_pk_f32_fp8((int)u, false);
  hi = __builtin_amdgcn_cvt_pk_f32_fp8((int)u, true);
#else
  __hip_fp8_e4m3 v0, v1, v2, v3;
  v0.__x = u & 0xFF; v1.__x = (u >> 8) & 0xFF;
  v2.__x = (u >> 16) & 0xFF; v3.__x = (u >> 24) & 0xFF;
  lo.x = (float)v0; lo.y = (float)v1; hi.x = (float)v2; hi.y = (float)v3;
#endif
}

__device__ inline unsigned enc4(float a, float b, float c, float d) {
#ifdef FP8_HW
  int w = __builtin_amdgcn_cvt_pk_fp8_f32(a, b, 0, false);
  w = __builtin_amdgcn_cvt_pk_fp8_f32(c, d, w, true);
  return (unsigned)w;
#else
  return (unsigned)__hip_fp8_e4m3(a).__x | ((unsigned)__hip_fp8_e4m3(b).__x << 8) |
         ((unsigned)__hip_fp8_e4m3(c).__x << 16) | ((unsigned)__hip_fp8_e4m3(d).__x << 24);
#endif
}

// 8 fp8 (two u32) -> 8 fp16 packed in a uint4
__device__ inline uint4 fp8x8_to_h8(unsigned ux, unsigned uy) {
  f32x2 lo, hi;
  HU p0, p1, p2, p3;
  dec4(ux, lo, hi);
  p0.h.x = (_Float16)lo.x; p0.h.y = (_Float16)lo.y;
  p1.h.x = (_Float16)hi.x; p1.h.y = (_Float16)hi.y;
  dec4(uy, lo, hi);
  p2.h.x = (_Float16)lo.x; p2.h.y = (_Float16)lo.y;
  p3.h.x = (_Float16)hi.x; p3.h.y = (_Float16)hi.y;
  return make_uint4(p0.u, p1.u, p2.u, p3.u);
}

// ---------------- K1: dual partition, ONE pass per block ----------------
// blocks 0..127: dst-partition (pairsD); 128..255: src-partition (pairsS).
// PCHUNK=12500 -> bucket runs ~32 entries = 128B (near-1x write amp).
// LDS ~82 KB -> 1 block/CU. Global atomics: 391 per block.

__global__ __launch_bounds__(PT) void partition_kernel(
    const float* __restrict__ x, unsigned char* __restrict__ h0,
    const int* __restrict__ src, const int* __restrict__ dst,
    int* __restrict__ gfillD, int* __restrict__ gfillS,
    unsigned* __restrict__ pairsD, unsigned* __restrict__ pairsS) {
  __shared__ unsigned ents[PCHUNK];       // 50.0 KB
  __shared__ unsigned short bkt[PCHUNK];  // 25.0 KB
  __shared__ int hist[NB], lfill[NB], delta[NB];
  __shared__ int sc[PT];

  const int blk = blockIdx.x & (PHB - 1);
  const int pass = blockIdx.x >> 7;       // 0: by-dst, 1: by-src
  const int t = threadIdx.x;
  const int e0 = blk * PCHUNK;
  const int* __restrict__ key = pass ? src : dst;
  const int* __restrict__ val = pass ? dst : src;
  int* __restrict__ gfill = pass ? gfillS : gfillD;
  unsigned* __restrict__ out = pass ? pairsS : pairsD;

  for (int i = t; i < NB; i += PT) hist[i] = 0;
  __syncthreads();
  for (int i = t; i < PCHUNK; i += PT) atomicAdd(&hist[key[e0 + i] >> 8], 1);
  __syncthreads();
  int v = (t < NB) ? hist[t] : 0;
  sc[t] = v;
  __syncthreads();
  for (int off = 1; off < PT; off <<= 1) {
    int a = (t >= off) ? sc[t - off] : 0;
    __syncthreads();
    sc[t] += a;
    __syncthreads();
  }
  if (t < NB) {
    int excl = sc[t] - v;
    lfill[t] = excl;
    int gb = atomicAdd(&gfill[t * 16], v);
    delta[t] = t * CAP + gb - excl;
  }
  __syncthreads();
  for (int i = t; i < PCHUNK; i += PT) {
    int k = key[e0 + i], w = val[e0 + i];
    int b = k >> 8;
    int p = atomicAdd(&lfill[b], 1);
    ents[p] = (unsigned)w | ((unsigned)(k & 255) << 17);
    bkt[p] = (unsigned short)b;
  }
  __syncthreads();
  for (int i = t; i < PCHUNK; i += PT) out[delta[bkt[i]] + i] = ents[i];

  // fused x -> fp8 convert (grid-stride over all 256 blocks)
  const int gtid = blockIdx.x * PT + t;
  const int nth = gridDim.x * PT;
  for (int i = gtid; i < N_NODES * 8; i += nth) {
    float4 a = ((const float4*)x)[2 * i];
    float4 b = ((const float4*)x)[2 * i + 1];
    ((uint2*)h0)[i] = make_uint2(enc4(a.x, a.y, a.z, a.w), enc4(b.x, b.y, b.z, b.w));
  }
}

// ---------------- K2: per-dst-bucket LDS counting sort ----------------

__global__ __launch_bounds__(256) void csr_kernel(const unsigned* __restrict__ pairs,
                                                  const int* __restrict__ bfill,
                                                  int* __restrict__ col,
                                                  int* __restrict__ rowptr,
                                                  int* __restrict__ cnt,
                                                  float* __restrict__ invdeg) {
  __shared__ int hist[256], sc[256], offs[256];
  const int b = blockIdx.x;
  const int t = threadIdx.x;
  hist[t] = 0;
  __syncthreads();
  const int count = bfill[b * 16];
  const int base = b * CAP;
  const unsigned* bp = pairs + (size_t)b * CAP;
  for (int i = t; i < count; i += 256) atomicAdd(&hist[(bp[i] >> 17) & 255], 1);
  __syncthreads();
  int v = hist[t];
  sc[t] = v;
  __syncthreads();
  for (int off = 1; off < 256; off <<= 1) {
    int a = (t >= off) ? sc[t - off] : 0;
    __syncthreads();
    sc[t] += a;
    __syncthreads();
  }
  const int excl = sc[t] - v;
  offs[t] = base + excl;
  const int node = b * 256 + t;
  if (node < N_NODES) {
    rowptr[node] = base + excl;
    cnt[node] = v;
    invdeg[node] = 1.0f / (float)((v > 0) ? v : 1);
  }
  __syncthreads();
  for (int i = t; i < count; i += 256) {
    unsigned e = bp[i];
    int p = atomicAdd(&offs[(e >> 17) & 255], 1);
    col[p] = (int)(e & 0x1FFFF);
  }
}

// ---------------- K3: coef via per-src-bucket LDS accumulation ----------------

__global__ __launch_bounds__(256) void coef_kernel(const unsigned* __restrict__ pairsS,
                                                   const int* __restrict__ gfillS,
                                                   const float* __restrict__ invdeg,
                                                   float* __restrict__ coef) {
  __shared__ float cl[256];
  const int b = blockIdx.x;
  const int t = threadIdx.x;
  cl[t] = 0.0f;
  __syncthreads();
  const int count = gfillS[b * 16];
  const unsigned* bp = pairsS + (size_t)b * CAP;
  for (int i = t; i < count; i += 256) {
    unsigned e = bp[i];
    atomicAdd(&cl[(e >> 17) & 255], invdeg[e & 0x1FFFF]);
  }
  __syncthreads();
  const int node = b * 256 + t;
  if (node < N_NODES) coef[node] = cl[t];
}

// ---------------- K4: gather/mean (latency path; aggr stored fp8) ----------------

__global__ __launch_bounds__(256) void gather_kernel(
    const unsigned char* __restrict__ hin, const int* __restrict__ rowptr,
    const int* __restrict__ cnt, const int* __restrict__ col,
    uint2* __restrict__ aggr8) {
  const int tid = threadIdx.x;
  const int lane = tid & 63;
  const int wv = tid >> 6;
  const int slot = lane >> 3;   // 0..7
  const int c = lane & 7;       // channel octet
  const int wid = blockIdx.x * 4 + wv;
  const int nwaves = gridDim.x * 4;
  const uint2* __restrict__ hrows = (const uint2*)hin;

  for (int oct = wid; oct < NOCT; oct += nwaves) {
    const int node = oct * 8 + slot;
    const int deg = cnt[node];
    const int* cp = col + rowptr[node];
    f32x2 a01 = {0.f, 0.f}, a23 = {0.f, 0.f}, a45 = {0.f, 0.f}, a67 = {0.f, 0.f};
    for (int e = 0; e < deg; e += 16) {
      uint2 u[16];
#pragma unroll
      for (int i = 0; i < 16; ++i) {
        int idx = (e + i < deg) ? (e + i) : (deg - 1);
        u[i] = hrows[cp[idx] * 8 + c];
      }
#pragma unroll
      for (int i = 0; i < 16; ++i) {
        const bool valid = (e + i) < deg;
        unsigned ux = valid ? u[i].x : 0u;
        unsigned uy = valid ? u[i].y : 0u;
        f32x2 lo, hi;
        dec4(ux, lo, hi); a01 += lo; a23 += hi;
        dec4(uy, lo, hi); a45 += lo; a67 += hi;
      }
    }
    const float inv = (deg > 0) ? (1.0f / (float)deg) : 0.0f;
    a01 *= inv; a23 *= inv; a45 *= inv; a67 *= inv;
    aggr8[(size_t)node * 8 + c] =
        make_uint2(enc4(a01.x, a01.y, a23.x, a23.y), enc4(a45.x, a45.y, a67.x, a67.y));
  }
}

// ---------------- K5: transform via MFMA (aggr fp8) ----------------
// [16-node tile x K=128 (aggr|own)] x W~[64][128]^T via mfma_f32_16x16x32_f16.

template <bool WRITE_OUT, bool DO_SUMS>
__global__ __launch_bounds__(256) void transform_kernel(
    const unsigned char* __restrict__ hin, const unsigned char* __restrict__ aggr8,
    const float* __restrict__ wl, const float* __restrict__ bl,
    const float* __restrict__ wr,
    const float* __restrict__ g, const float* __restrict__ be,
    const float* __restrict__ m, const float* __restrict__ v,
    unsigned char* __restrict__ hout, const float* __restrict__ coef,
    float* __restrict__ sums) {
  __shared__ _Float16 Wt[64][136];     // W~[j][k], padded stride
  __shared__ _Float16 Xs[4][16][136];  // per-wave X tile
  __shared__ float Ts[4][16][68];      // per-wave transpose buf
  __shared__ float scaleS[64], shiftS[64];
  __shared__ float redS[4][128];

  const int tid = threadIdx.x;
  {
    int j = tid >> 2, kp = (tid & 3) * 32;
    for (int kk = 0; kk < 32; ++kk) {
      int k = kp + kk;
      float val = (k < 64) ? wl[j * 64 + k] : wr[j * 64 + (k - 64)];
      Wt[j][k] = (_Float16)val;
    }
  }
  if (tid < 64) {
    float sc = rsqrtf(v[tid] + 1e-5f) * g[tid];
    scaleS[tid] = sc;
    shiftS[tid] = bl[tid] * sc + be[tid] - m[tid] * sc;
  }
  __syncthreads();

  const int lane = tid & 63;
  const int wv = tid >> 6;
  const int c = lane & 15;
  const int gq = lane >> 4;            // k-group / row-group
  const int wid = blockIdx.x * 4 + wv;
  const int nwv = gridDim.x * 4;
  float accs[4] = {0.f, 0.f, 0.f, 0.f};
  float accs2[4] = {0.f, 0.f, 0.f, 0.f};

  for (int tile = wid; tile < NTILE; tile += nwv) {
    const int nb = tile * 16;

    // ---- stage X (same-wave produce/consume, no barrier) ----
    {
      int node = lane >> 2, q4 = lane & 3;   // 16B per lane covers 16 rows x 64B
      uint4 av = ((const uint4*)(aggr8 + (size_t)nb * 64))[lane];
      *(uint4*)&Xs[wv][node][q4 * 16] = fp8x8_to_h8(av.x, av.y);
      *(uint4*)&Xs[wv][node][q4 * 16 + 8] = fp8x8_to_h8(av.z, av.w);
      uint4 ov = ((const uint4*)(hin + (size_t)nb * 64))[lane];
      *(uint4*)&Xs[wv][node][64 + q4 * 16] = fp8x8_to_h8(ov.x, ov.y);
      *(uint4*)&Xs[wv][node][64 + q4 * 16 + 8] = fp8x8_to_h8(ov.z, ov.w);
    }

    // ---- A fragments (reused across 4 col-tiles) ----
    half8 A[4];
#pragma unroll
    for (int mm = 0; mm < 4; ++mm)
      A[mm] = *(const half8*)&Xs[wv][c][mm * 32 + gq * 8];

    f32x4 acc[4];
#pragma unroll
    for (int t = 0; t < 4; ++t) {
      acc[t] = (f32x4){0.f, 0.f, 0.f, 0.f};
#pragma unroll
      for (int mm = 0; mm < 4; ++mm) {
        half8 B = *(const half8*)&Wt[t * 16 + c][mm * 32 + gq * 8];
        acc[t] = __builtin_amdgcn_mfma_f32_16x16x32_f16(A[mm], B, acc[t], 0, 0, 0);
      }
    }

    // ---- epilogue: BN + ReLU ----
    float cf[4];
    if (DO_SUMS) {
#pragma unroll
      for (int r = 0; r < 4; ++r) cf[r] = coef[nb + gq * 4 + r];
    }
#pragma unroll
    for (int t = 0; t < 4; ++t) {
      const int colj = t * 16 + c;
      const float sc = scaleS[colj], sh = shiftS[colj];
#pragma unroll
      for (int r = 0; r < 4; ++r) {
        float o = fmaxf(acc[t][r] * sc + sh, 0.0f);
        if (DO_SUMS) {
          accs[t] += o;
          accs2[t] += cf[r] * o;
        }
        if (WRITE_OUT) Ts[wv][gq * 4 + r][colj] = o;
      }
    }

    if (WRITE_OUT) {
      int node = lane >> 4, q = lane & 15;
#pragma unroll
      for (int i = 0; i < 4; ++i) {
        float4 vv = *(float4*)&Ts[wv][node + 4 * i][q * 4];
        ((unsigned*)hout)[(size_t)(nb + node + 4 * i) * 16 + q] =
            enc4(vv.x, vv.y, vv.z, vv.w);
      }
    }
  }

  if (DO_SUMS) {
#pragma unroll
    for (int t = 0; t < 4; ++t) {
      float a = accs[t], b2 = accs2[t];
      a += __shfl_xor(a, 16); a += __shfl_xor(a, 32);
      b2 += __shfl_xor(b2, 16); b2 += __shfl_xor(b2, 32);
      if (lane < 16) {
        redS[wv][t * 16 + lane] = a;
        redS[wv][64 + t * 16 + lane] = b2;
      }
    }
    __syncthreads();
    if (tid < 128) {
      float tot = redS[0][tid] + redS[1][tid] + redS[2][tid] + redS[3][tid];
      atomicAdd(&sums[tid], tot);
    }
  }
}

// ---------------- collapsed layer 2 + classifier + sigmoid ----------------

__global__ void final_kernel(const float* __restrict__ sums,
                             const float* __restrict__ wl2, const float* __restrict__ bl2,
                             const float* __restrict__ wr2,
                             const float* __restrict__ cw1, const float* __restrict__ cb1,
                             const float* __restrict__ cw2, const float* __restrict__ cb2,
                             float* __restrict__ out) {
  __shared__ float maS[64], mhS[64], m3S[64], tS[64];
  int j = threadIdx.x;  // 64 threads
  float invN = 1.0f / (float)N_NODES;
  mhS[j] = sums[j] * invN;        // mean of h2
  maS[j] = sums[64 + j] * invN;   // mean of aggr3
  __syncthreads();
  float acc = bl2[j];
#pragma unroll
  for (int k = 0; k < 64; ++k)
    acc += wl2[j * 64 + k] * maS[k] + wr2[j * 64 + k] * mhS[k];
  m3S[j] = acc;
  __syncthreads();
  float c = cb1[j];
#pragma unroll
  for (int k = 0; k < 64; ++k) c += cw1[j * 64 + k] * m3S[k];
  tS[j] = fmaxf(c, 0.f);
  __syncthreads();
  float r = tS[j] * cw2[j];
#pragma unroll
  for (int off = 32; off > 0; off >>= 1) r += __shfl_down(r, off);
  if (j == 0) out[0] = 1.0f / (1.0f + expf(-(r + cb2[0])));
}

// ---------------- host launcher ----------------

extern "C" void kernel_launch(void* const* d_in, const int* in_sizes, int n_in,
                              void* d_out, int out_size, void* d_ws, size_t ws_size,
                              hipStream_t stream) {
  const float* x   = (const float*)d_in[0];
  const int* ei    = (const int*)d_in[1];
  const float* wl0 = (const float*)d_in[2];
  const float* bl0 = (const float*)d_in[3];
  const float* wr0 = (const float*)d_in[4];
  const float* wl1 = (const float*)d_in[5];
  const float* bl1 = (const float*)d_in[6];
  const float* wr1 = (const float*)d_in[7];
  const float* wl2 = (const float*)d_in[8];
  const float* bl2 = (const float*)d_in[9];
  const float* wr2 = (const float*)d_in[10];
  const float* g0  = (const float*)d_in[11];
  const float* be0 = (const float*)d_in[12];
  const float* m0  = (const float*)d_in[13];
  const float* v0  = (const float*)d_in[14];
  const float* g1  = (const float*)d_in[15];
  const float* be1 = (const float*)d_in[16];
  const float* m1  = (const float*)d_in[17];
  const float* v1  = (const float*)d_in[18];
  const float* cw1 = (const float*)d_in[19];
  const float* cb1 = (const float*)d_in[20];
  const float* cw2 = (const float*)d_in[21];
  const float* cb2 = (const float*)d_in[22];

  const int* srcp = ei;            // edge_index[0]
  const int* dstp = ei + N_EDGES;  // edge_index[1]

  char* ws = (char*)d_ws;
  size_t off = 0;
  auto alloc = [&](size_t bytes) {
    void* p = ws + off;
    off = align256(off + bytes);
    return p;
  };
  // gfillD | gfillS | sums contiguous -> ONE memset
  int* gfillD      = (int*)alloc((size_t)512 * 16 * 4);   // 32 KB
  int* gfillS      = (int*)alloc((size_t)512 * 16 * 4);   // 32 KB
  float* sums      = (float*)alloc(128 * 4);              // 512 B
  unsigned* pairsD = (unsigned*)alloc((size_t)NB * CAP * 4);  // ~8 MB
  unsigned* pairsS = (unsigned*)alloc((size_t)NB * CAP * 4);  // ~8 MB
  int* rowptr      = (int*)alloc((size_t)N_NODES * 4);
  int* cnt         = (int*)alloc((size_t)N_NODES * 4);
  float* invdeg    = (float*)alloc((size_t)N_NODES * 4);
  float* coef      = (float*)alloc((size_t)N_NODES * 4);
  int* col         = (int*)alloc((size_t)NB * CAP * 4);       // padded per bucket
  unsigned char* h0 = (unsigned char*)alloc((size_t)N_NODES * 64);
  unsigned char* h1 = (unsigned char*)alloc((size_t)N_NODES * 64);
  uint2* aggr8     = (uint2*)alloc((size_t)N_NODES * 64);     // fp8 aggr, 6.4 MB
  (void)off; (void)ws_size; (void)in_sizes; (void)n_in; (void)out_size;

  (void)hipMemsetAsync(gfillD, 0, (size_t)512 * 16 * 4 * 2 + 512, stream);

  partition_kernel<<<256, PT, 0, stream>>>(x, h0, srcp, dstp,
                                           gfillD, gfillS, pairsD, pairsS);
  csr_kernel<<<NB, 256, 0, stream>>>(pairsD, gfillD, col, rowptr, cnt, invdeg);
  coef_kernel<<<NB, 256, 0, stream>>>(pairsS, gfillS, invdeg, coef);

  // layer 0
  gather_kernel<<<2048, 256, 0, stream>>>(h0, rowptr, cnt, col, aggr8);
  transform_kernel<true, false><<<512, 256, 0, stream>>>(
      h0, (const unsigned char*)aggr8, wl0, bl0, wr0, g0, be0, m0, v0,
      h1, nullptr, nullptr);
  // layer 1 (+ collapsed layer 2 sums)
  gather_kernel<<<2048, 256, 0, stream>>>(h1, rowptr, cnt, col, aggr8);
  transform_kernel<false, true><<<512, 256, 0, stream>>>(
      h1, (const unsigned char*)aggr8, wl1, bl1, wr1, g1, be1, m1, v1,
      nullptr, coef, sums);

  final_kernel<<<1, 64, 0, stream>>>(sums, wl2, bl2, wr2, cw1, cb1, cw2, cb2,
                                     (float*)d_out);
}